// Round 2
// baseline (1673.182 us; speedup 1.0000x reference)
//
#include <hip/hip_runtime.h>
#include <math.h>

#define DEPTH 6
#define DIM 1024
#define HEADS 16
#define DH 64
#define INNER 2730
#define INNER2 5460
#define INNERP 2752      // INNER padded to 64
#define N1P 5504         // INNER2 padded to 128
#define BATCH 2
#define SEQ 1024
#define TOK (BATCH*SEQ)
#define QKVW 1152        // 1024 q + 64 k + 64 v

// per-layer transposed-weight layout (elems)
#define OFF_WO 1179648ull                  // after qkv (1152*1024)
#define OFF_W1 2228224ull                  // + wo (1024*1024)
#define OFF_W2 7864320ull                  // + w1 (5504*1024)
#define LWT    10682368ull                 // + w2 (1024*2752)
#define TILES_PER_LAYER 2608               // 288 qkv + 256 wo + 1376 w1 + 688 w2

typedef unsigned short ushort;
typedef __attribute__((ext_vector_type(8))) short short8;
typedef __attribute__((ext_vector_type(4))) short short4v;
typedef __attribute__((ext_vector_type(4))) unsigned short ushort4v;
typedef __attribute__((ext_vector_type(2))) unsigned short ushort2v;
typedef __attribute__((ext_vector_type(4))) float floatx4;

__device__ inline ushort f2bf(float f) {
  unsigned int u = __float_as_uint(f);
  u += 0x7FFF + ((u >> 16) & 1);
  return (ushort)(u >> 16);
}
__device__ inline float bf2f(ushort u) {
  return __uint_as_float(((unsigned int)u) << 16);
}

__device__ inline void gload_lds16(const ushort* g, ushort* l) {
  __builtin_amdgcn_global_load_lds(
      (const __attribute__((address_space(1))) unsigned int*)g,
      (__attribute__((address_space(3))) unsigned int*)l, 16, 0, 0);
}

// ---------------- bias fragment table ----------------
// bias_c[h][dq][rowgrp(16)][j(4)][col(16)][reg(4)]
__global__ void bias_frag_kernel(const float* __restrict__ rel_emb, float* __restrict__ bias_c) {
  int h = blockIdx.x >> 4, dq = blockIdx.x & 15;
  for (int i = threadIdx.x; i < 4096; i += 256) {
    int reg = i & 3, col = (i >> 2) & 15, j = (i >> 6) & 3, rowgrp = i >> 8;
    int row = rowgrp * 4 + reg, colg = j * 16 + col;
    int d = dq * 64 + row - colg;
    d = d < 0 ? 0 : (d > 1023 ? 1023 : d);
    int bucket;
    if (d < 16) {
      bucket = d;
    } else {
      float nf = (float)d;
      int vl = 16 + (int)(logf(nf / 16.0f) / 2.0794415416798357f * 16.0f);
      bucket = vl < 31 ? vl : 31;
    }
    bias_c[((size_t)(h * 16 + dq)) * 4096 + i] = rel_emb[bucket * HEADS + h];
  }
}

// ---------------- vectorized transpose + f32->bf16: W[K x N] -> Wt[Np x Kp] ----------------
// float4 reads, LDS-transposed staging t[n][k], short8 (16B) stores.
__device__ inline void transpose_body(const float* __restrict__ W, ushort* __restrict__ Wt,
                                      int K, int N, int Kp, int Np, float scale,
                                      int k0, int n0, size_t dst_row0) {
  __shared__ float t[64][65];   // t[n][k]
  int tid = threadIdx.x;
  int kl = tid >> 4, nc = (tid & 15) * 4;
#pragma unroll
  for (int it = 0; it < 4; it++) {
    int k = kl + it * 16;
    int gk = k0 + k, gn = n0 + nc;
    floatx4 v = {0.f, 0.f, 0.f, 0.f};
    if (gk < K && gn < N) v = *(const floatx4*)&W[(size_t)gk * N + gn];
    t[nc + 0][k] = v[0] * scale;
    t[nc + 1][k] = v[1] * scale;
    t[nc + 2][k] = v[2] * scale;
    t[nc + 3][k] = v[3] * scale;
  }
  __syncthreads();
  int nr = tid >> 3, q = tid & 7;
#pragma unroll
  for (int it = 0; it < 2; it++) {
    int n = nr + it * 32;
    if (n0 + n < Np) {
      short8 p;
#pragma unroll
      for (int e = 0; e < 8; e++) p[e] = (short)f2bf(t[n][q * 8 + e]);
      *(short8*)&Wt[(dst_row0 + n) * Kp + k0 + q * 8] = p;
    }
  }
}

__global__ __launch_bounds__(256) void transpose_vec(const float* __restrict__ W,
                                                     ushort* __restrict__ Wt,
                                                     int K, int N, int Kp, int Np, float scale) {
  transpose_body(W, Wt, K, N, Kp, Np, scale, blockIdx.y * 64, blockIdx.x * 64,
                 (size_t)blockIdx.x * 64);
}

// fused wq (scaled) + wkv transpose into one [1152 x 1024] buffer. grid (18,16)
__global__ __launch_bounds__(256) void transpose_qkv(const float* __restrict__ wq,
                                                     const float* __restrict__ wkv,
                                                     ushort* __restrict__ Wt) {
  int bx = blockIdx.x;
  if (bx < 16) {
    transpose_body(wq, Wt, 1024, 1024, 1024, 1024, 0.125f, blockIdx.y * 64, bx * 64,
                   (size_t)bx * 64);
  } else {
    transpose_body(wkv, Wt, 1024, 128, 1024, 128, 1.0f, blockIdx.y * 64, (bx - 16) * 64,
                   (size_t)1024 + (bx - 16) * 64);
  }
}

// all-layer batched weight transpose: one launch does every per-layer transpose.
// linear tile id -> (layer, weight, tile). Uniform branch per block.
__global__ __launch_bounds__(256) void transpose_all(const float* __restrict__ wq,
                                                     const float* __restrict__ wkv,
                                                     const float* __restrict__ wo,
                                                     const float* __restrict__ w1,
                                                     const float* __restrict__ w2,
                                                     ushort* __restrict__ wtall) {
  int t = blockIdx.x;
  int l = t / TILES_PER_LAYER, r = t % TILES_PER_LAYER;
  ushort* base = wtall + (size_t)l * LWT;
  if (r < 288) {                       // qkv: grid (18,16)
    int bx = r % 18, by = r / 18;
    if (bx < 16)
      transpose_body(wq + (size_t)l * 1024 * 1024, base, 1024, 1024, 1024, 1024,
                     0.125f, by * 64, bx * 64, (size_t)bx * 64);
    else
      transpose_body(wkv + (size_t)l * 1024 * 128, base, 1024, 128, 1024, 128,
                     1.0f, by * 64, (bx - 16) * 64, 1024 + (size_t)(bx - 16) * 64);
  } else if (r < 544) {                // wo: grid (16,16)
    int q = r - 288, bx = q & 15, by = q >> 4;
    transpose_body(wo + (size_t)l * 1024 * 1024, base + OFF_WO, 1024, 1024, 1024, 1024,
                   1.0f, by * 64, bx * 64, (size_t)bx * 64);
  } else if (r < 1920) {               // w1: grid (86,16)
    int q = r - 544, bx = q % 86, by = q / 86;
    transpose_body(w1 + (size_t)l * 1024 * 5460, base + OFF_W1, 1024, 5460, 1024, 5504,
                   1.0f, by * 64, bx * 64, (size_t)bx * 64);
  } else {                             // w2: grid (16,43)
    int q = r - 1920, bx = q & 15, by = q >> 4;
    transpose_body(w2 + (size_t)l * 2730 * 1024, base + OFF_W2, 2730, 1024, 2752, 1024,
                   1.0f, by * 64, bx * 64, (size_t)bx * 64);
  }
}

// ---------------- LayerNorm specialized for 1024 cols ----------------
template <typename OutT>
__global__ __launch_bounds__(256) void ln1024(const float* __restrict__ in,
                                              const float* __restrict__ g,
                                              OutT* __restrict__ out) {
  int row = blockIdx.x;
  int tid = threadIdx.x;
  floatx4 v = *(const floatx4*)&in[(size_t)row * 1024 + tid * 4];
  float s = v[0] + v[1] + v[2] + v[3];
  float ss = v[0] * v[0] + v[1] * v[1] + v[2] * v[2] + v[3] * v[3];
#pragma unroll
  for (int off = 32; off; off >>= 1) {
    s  += __shfl_down(s, off, 64);
    ss += __shfl_down(ss, off, 64);
  }
  __shared__ float l1[4], l2[4];
  int wid = tid >> 6, lane = tid & 63;
  if (lane == 0) { l1[wid] = s; l2[wid] = ss; }
  __syncthreads();
  if (tid == 0) {
    float a = l1[0] + l1[1] + l1[2] + l1[3];
    float bb = l2[0] + l2[1] + l2[2] + l2[3];
    float m = a * (1.0f / 1024.0f);
    float var = bb * (1.0f / 1024.0f) - m * m;
    l1[0] = m;
    l2[0] = rsqrtf(var + 1e-5f);
  }
  __syncthreads();
  float m = l1[0], r = l2[0];
  floatx4 gv = *(const floatx4*)&g[tid * 4];
  if constexpr (sizeof(OutT) == 2) {
    short4v p;
#pragma unroll
    for (int e = 0; e < 4; e++) p[e] = (short)f2bf((v[e] - m) * r * gv[e]);
    *(short4v*)&out[(size_t)row * 1024 + tid * 4] = p;
  } else {
    floatx4 p;
#pragma unroll
    for (int e = 0; e < 4; e++) p[e] = (v[e] - m) * r * gv[e];
    *(floatx4*)&out[(size_t)row * 1024 + tid * 4] = p;
  }
}

// ---------------- bf16 MFMA GEMM, 128x128 tile ----------------
template <bool ADD, typename OutT>
__global__ __launch_bounds__(256) void gemm_mfma128(const ushort* __restrict__ A,
                                                    const ushort* __restrict__ Bt,
                                                    const float* __restrict__ Cin,
                                                    OutT* __restrict__ C,
                                                    int N, int K, float scale) {
  __shared__ ushort Als[128 * 64];
  __shared__ ushort Bls[128 * 64];
  int tid = threadIdx.x;
  int w = tid >> 6, lane = tid & 63;
  int wr = w >> 1, wc = w & 1;
  size_t row0 = (size_t)blockIdx.y * 128, col0 = (size_t)blockIdx.x * 128;

  const ushort* Ag = A + (row0 + w * 32 + (lane >> 3)) * (size_t)K + (lane & 7) * 8;
  const ushort* Bg = Bt + (col0 + w * 32 + (lane >> 3)) * (size_t)K + (lane & 7) * 8;
  ushort* Al = Als + w * 32 * 64;
  ushort* Bl = Bls + w * 32 * 64;

  floatx4 acc[4][4];
#pragma unroll
  for (int i = 0; i < 4; i++)
#pragma unroll
    for (int j = 0; j < 4; j++) { floatx4 z = {0.f, 0.f, 0.f, 0.f}; acc[i][j] = z; }

  int mrow = lane & 15, kq = (lane >> 4) * 8;
  for (int k0 = 0; k0 < K; k0 += 64) {
#pragma unroll
    for (int r = 0; r < 4; r++) {
      gload_lds16(Ag + (size_t)(r * 8) * K + k0, Al + r * 8 * 64);
      gload_lds16(Bg + (size_t)(r * 8) * K + k0, Bl + r * 8 * 64);
    }
    __syncthreads();
#pragma unroll
    for (int kk = 0; kk < 64; kk += 32) {
      short8 a[4], b[4];
#pragma unroll
      for (int i = 0; i < 4; i++)
        a[i] = *(const short8*)&Als[(wr * 64 + i * 16 + mrow) * 64 + kk + kq];
#pragma unroll
      for (int j = 0; j < 4; j++)
        b[j] = *(const short8*)&Bls[(wc * 64 + j * 16 + mrow) * 64 + kk + kq];
#pragma unroll
      for (int i = 0; i < 4; i++)
#pragma unroll
        for (int j = 0; j < 4; j++)
          acc[i][j] = __builtin_amdgcn_mfma_f32_16x16x32_bf16(a[i], b[j], acc[i][j], 0, 0, 0);
    }
    __syncthreads();
  }
  int orow = (lane >> 4) * 4, ocol = lane & 15;
#pragma unroll
  for (int i = 0; i < 4; i++) {
#pragma unroll
    for (int ii = 0; ii < 4; ii++) {
      size_t gr = row0 + wr * 64 + i * 16 + orow + ii;
#pragma unroll
      for (int j = 0; j < 4; j++) {
        size_t gc = col0 + wc * 64 + j * 16 + ocol;
        float v = acc[i][j][ii] * scale;
        if (ADD) v += Cin[gr * N + gc];
        if constexpr (sizeof(OutT) == 2) C[gr * N + gc] = f2bf(v);
        else C[gr * N + gc] = v;
      }
    }
  }
}

// ---------------- bf16 MFMA GEMM, 128x64 tile ----------------
template <bool ADD, typename OutT>
__global__ __launch_bounds__(256) void gemm_mfma64(const ushort* __restrict__ A,
                                                   const ushort* __restrict__ Bt,
                                                   const float* __restrict__ Cin,
                                                   OutT* __restrict__ C,
                                                   int N, int K, float scale) {
  __shared__ ushort Als[128 * 64];
  __shared__ ushort Bls[64 * 64];
  int tid = threadIdx.x;
  int w = tid >> 6, lane = tid & 63;
  size_t row0 = (size_t)blockIdx.y * 128, col0 = (size_t)blockIdx.x * 64;

  const ushort* Ag = A + (row0 + w * 32 + (lane >> 3)) * (size_t)K + (lane & 7) * 8;
  const ushort* Bg = Bt + (col0 + w * 16 + (lane >> 3)) * (size_t)K + (lane & 7) * 8;
  ushort* Al = Als + w * 32 * 64;
  ushort* Bl = Bls + w * 16 * 64;

  floatx4 acc[2][4];
#pragma unroll
  for (int i = 0; i < 2; i++)
#pragma unroll
    for (int j = 0; j < 4; j++) { floatx4 z = {0.f, 0.f, 0.f, 0.f}; acc[i][j] = z; }

  int mrow = lane & 15, kq = (lane >> 4) * 8;
  for (int k0 = 0; k0 < K; k0 += 64) {
#pragma unroll
    for (int r = 0; r < 4; r++)
      gload_lds16(Ag + (size_t)(r * 8) * K + k0, Al + r * 8 * 64);
#pragma unroll
    for (int r = 0; r < 2; r++)
      gload_lds16(Bg + (size_t)(r * 8) * K + k0, Bl + r * 8 * 64);
    __syncthreads();
#pragma unroll
    for (int kk = 0; kk < 64; kk += 32) {
      short8 a[2], b[4];
#pragma unroll
      for (int i = 0; i < 2; i++)
        a[i] = *(const short8*)&Als[(w * 32 + i * 16 + mrow) * 64 + kk + kq];
#pragma unroll
      for (int j = 0; j < 4; j++)
        b[j] = *(const short8*)&Bls[(j * 16 + mrow) * 64 + kk + kq];
#pragma unroll
      for (int i = 0; i < 2; i++)
#pragma unroll
        for (int j = 0; j < 4; j++)
          acc[i][j] = __builtin_amdgcn_mfma_f32_16x16x32_bf16(a[i], b[j], acc[i][j], 0, 0, 0);
    }
    __syncthreads();
  }
  int orow = (lane >> 4) * 4, ocol = lane & 15;
#pragma unroll
  for (int i = 0; i < 2; i++) {
#pragma unroll
    for (int ii = 0; ii < 4; ii++) {
      size_t gr = row0 + w * 32 + i * 16 + orow + ii;
#pragma unroll
      for (int j = 0; j < 4; j++) {
        size_t gc = col0 + j * 16 + ocol;
        float v = acc[i][j][ii] * scale;
        if (ADD) v += Cin[gr * N + gc];
        if constexpr (sizeof(OutT) == 2) C[gr * N + gc] = f2bf(v);
        else C[gr * N + gc] = v;
      }
    }
  }
}

// ---------------- fused causal conv(3) + GLU(gelu exact) + LayerNorm -> bf16 padded ----------------
// one block per token; vals kept in registers; block-reduce mean/var over INNER.
__global__ __launch_bounds__(256) void convglu_ln(const ushort* __restrict__ h1,
                                                  const float* __restrict__ cw,
                                                  const float* __restrict__ lng,
                                                  ushort* __restrict__ out) {
  int t = blockIdx.x;
  int n = t & (SEQ - 1);
  int tid = threadIdx.x;
  const ushort* r0 = h1 + (size_t)t * N1P;
  float vals[3][4];
  float s = 0.f, ss = 0.f;
#pragma unroll
  for (int it = 0; it < 3; it++) {
    int c = (it * 256 + tid) * 4;
#pragma unroll
    for (int e = 0; e < 4; e++) vals[it][e] = 0.f;
    if (c < INNER) {
      ushort4v a2 = *(const ushort4v*)&r0[c];
      ushort4v a1 = {0, 0, 0, 0}, a0 = {0, 0, 0, 0};
      if (n >= 1) a1 = *(const ushort4v*)&r0[c - N1P];
      if (n >= 2) a0 = *(const ushort4v*)&r0[c - 2 * N1P];
      int cg = c + INNER;   // ≡ 2 mod 4 -> two 4B-aligned ushort2 loads per row
      ushort2v g2a = *(const ushort2v*)&r0[cg];
      ushort2v g2b = *(const ushort2v*)&r0[cg + 2];
      ushort2v g1a = {0, 0}, g1b = {0, 0}, g0a = {0, 0}, g0b = {0, 0};
      if (n >= 1) { g1a = *(const ushort2v*)&r0[cg - N1P]; g1b = *(const ushort2v*)&r0[cg + 2 - N1P]; }
      if (n >= 2) { g0a = *(const ushort2v*)&r0[cg - 2 * N1P]; g0b = *(const ushort2v*)&r0[cg + 2 - 2 * N1P]; }
      const floatx4* cwa = (const floatx4*)(cw + (size_t)c * 3);   // 16B-aligned (48*g bytes)
      floatx4 f0 = cwa[0], f1 = cwa[1], f2 = cwa[2];
      float wa[12] = {f0[0], f0[1], f0[2], f0[3], f1[0], f1[1], f1[2], f1[3],
                      f2[0], f2[1], f2[2], f2[3]};
#pragma unroll
      for (int e = 0; e < 4; e++) {
        int ce = c + e;
        if (ce < INNER) {
          float av = bf2f(a0[e]) * wa[e * 3] + bf2f(a1[e]) * wa[e * 3 + 1] +
                     bf2f(a2[e]) * wa[e * 3 + 2];
          int cge = ce + INNER;
          float w0g = cw[cge * 3], w1g = cw[cge * 3 + 1], w2g = cw[cge * 3 + 2];
          float g0f = bf2f(e < 2 ? g0a[e & 1] : g0b[e & 1]);
          float g1f = bf2f(e < 2 ? g1a[e & 1] : g1b[e & 1]);
          float g2f = bf2f(e < 2 ? g2a[e & 1] : g2b[e & 1]);
          float gvv = g0f * w0g + g1f * w1g + g2f * w2g;
          float gl = 0.5f * gvv * (1.0f + erff(gvv * 0.70710678118654752f));
          float val = gl * av;
          vals[it][e] = val;
          s += val;
          ss += val * val;
        }
      }
    }
  }
  // block reduction over INNER values
#pragma unroll
  for (int off = 32; off; off >>= 1) {
    s  += __shfl_down(s, off, 64);
    ss += __shfl_down(ss, off, 64);
  }
  __shared__ float l1[4], l2[4];
  int wid = tid >> 6, lane = tid & 63;
  if (lane == 0) { l1[wid] = s; l2[wid] = ss; }
  __syncthreads();
  if (tid == 0) {
    float a = l1[0] + l1[1] + l1[2] + l1[3];
    float bb = l2[0] + l2[1] + l2[2] + l2[3];
    float m = a * (1.0f / INNER);
    float var = bb * (1.0f / INNER) - m * m;
    l1[0] = m;
    l2[0] = rsqrtf(var + 1e-5f);
  }
  __syncthreads();
  float m = l1[0], r = l2[0];
#pragma unroll
  for (int it = 0; it < 3; it++) {
    int c = (it * 256 + tid) * 4;
    if (c < INNERP) {
      short4v p;
#pragma unroll
      for (int e = 0; e < 4; e++) {
        int ce = c + e;
        p[e] = (ce < INNER) ? (short)f2bf((vals[it][e] - m) * r * lng[ce]) : (short)0;
      }
      *(short4v*)&out[(size_t)t * INNERP + c] = p;
    }
  }
}

// ---------------- MFMA flash attention ----------------
__global__ __launch_bounds__(256) void attn_mfma(const ushort* __restrict__ qkv,
                                                 const float* __restrict__ bias_c,
                                                 ushort* __restrict__ o) {
  __shared__ ushort Ks[64 * 72];
  __shared__ ushort Vt[64 * 72];
  __shared__ ushort Ps[64 * 72];
  __shared__ float arow[64];
  int tid = threadIdx.x;
  int lane = tid & 63, w = tid >> 6;
  int quad = lane >> 4, col = lane & 15;
  int b = blockIdx.x >> 4, h = blockIdx.x & 15;
  int y = blockIdx.y;
  int qt = (y < 8) ? (15 - y) : (y - 8);

  const ushort* qrow = qkv + (size_t)(b * SEQ + qt * 64 + w * 16 + col) * QKVW + h * 64;
  short8 qa[2];
  qa[0] = *(const short8*)&qrow[quad * 8];
  qa[1] = *(const short8*)&qrow[32 + quad * 8];

  float m_[4], l_[4];
  floatx4 oacc[4];
#pragma unroll
  for (int r = 0; r < 4; r++) { m_[r] = -1e30f; l_[r] = 0.f; }
#pragma unroll
  for (int mt = 0; mt < 4; mt++) { floatx4 z = {0.f, 0.f, 0.f, 0.f}; oacc[mt] = z; }

  for (int kc = 0; kc <= qt; kc++) {
    const ushort* kvb = qkv + (size_t)(b * SEQ + kc * 64) * QKVW;
#pragma unroll
    for (int it = 0; it < 2; it++) {
      int r = lane;
      int c8 = w + it * 4;
      short8 kk8 = *(const short8*)&kvb[(size_t)r * QKVW + 1024 + c8 * 8];
      *(short8*)&Ks[r * 72 + c8 * 8] = kk8;
      short8 vv = *(const short8*)&kvb[(size_t)r * QKVW + 1088 + c8 * 8];
#pragma unroll
      for (int e = 0; e < 8; e++) Vt[(c8 * 8 + e) * 72 + r] = (ushort)vv[e];
    }
    __syncthreads();

    floatx4 sarr[4];
#pragma unroll
    for (int j = 0; j < 4; j++) { floatx4 z = {0.f, 0.f, 0.f, 0.f}; sarr[j] = z; }
#pragma unroll
    for (int kk = 0; kk < 2; kk++) {
#pragma unroll
      for (int j = 0; j < 4; j++) {
        short8 kb = *(const short8*)&Ks[(j * 16 + col) * 72 + kk * 32 + quad * 8];
        sarr[j] = __builtin_amdgcn_mfma_f32_16x16x32_bf16(qa[kk], kb, sarr[j], 0, 0, 0);
      }
    }

    int dq = qt - kc;
    const floatx4* bc = (const floatx4*)(bias_c + ((size_t)(h * 16 + dq) * 4096 + (w * 4 + quad) * 256));
    float pv[4][4];
#pragma unroll
    for (int j = 0; j < 4; j++) {
      floatx4 bf = bc[j * 16 + col];
#pragma unroll
      for (int reg = 0; reg < 4; reg++) {
        float v = sarr[j][reg] + bf[reg];
        if (dq == 0 && (j * 16 + col) > (w * 16 + quad * 4 + reg)) v = -1e30f;
        pv[j][reg] = v;
      }
    }

#pragma unroll
    for (int reg = 0; reg < 4; reg++) {
      float cm = fmaxf(fmaxf(pv[0][reg], pv[1][reg]), fmaxf(pv[2][reg], pv[3][reg]));
      cm = fmaxf(cm, __shfl_xor(cm, 1, 64));
      cm = fmaxf(cm, __shfl_xor(cm, 2, 64));
      cm = fmaxf(cm, __shfl_xor(cm, 4, 64));
      cm = fmaxf(cm, __shfl_xor(cm, 8, 64));
      float nm = fmaxf(m_[reg], cm);
      float alpha = __expf(m_[reg] - nm);
      float rs = 0.f;
#pragma unroll
      for (int j = 0; j < 4; j++) {
        float e = __expf(pv[j][reg] - nm);
        pv[j][reg] = e;
        rs += e;
      }
      rs += __shfl_xor(rs, 1, 64);
      rs += __shfl_xor(rs, 2, 64);
      rs += __shfl_xor(rs, 4, 64);
      rs += __shfl_xor(rs, 8, 64);
      l_[reg] = l_[reg] * alpha + rs;
      m_[reg] = nm;
      if (col == 0) arow[w * 16 + quad * 4 + reg] = alpha;
    }

#pragma unroll
    for (int j = 0; j < 4; j++)
#pragma unroll
      for (int reg = 0; reg < 4; reg++)
        Ps[(w * 16 + quad * 4 + reg) * 72 + j * 16 + col] = f2bf(pv[j][reg]);

    asm volatile("s_waitcnt lgkmcnt(0)" ::: "memory");
    float aval = arow[w * 16 + col];
#pragma unroll
    for (int mt = 0; mt < 4; mt++) oacc[mt] *= aval;

#pragma unroll
    for (int kk = 0; kk < 2; kk++) {
      short8 pb = *(const short8*)&Ps[(w * 16 + col) * 72 + kk * 32 + quad * 8];
#pragma unroll
      for (int mt = 0; mt < 4; mt++) {
        short8 va = *(const short8*)&Vt[(mt * 16 + col) * 72 + kk * 32 + quad * 8];
        oacc[mt] = __builtin_amdgcn_mfma_f32_16x16x32_bf16(va, pb, oacc[mt], 0, 0, 0);
      }
    }
    __syncthreads();
  }

#pragma unroll
  for (int reg = 0; reg < 4; reg++)
    if (col == 0) arow[w * 16 + quad * 4 + reg] = 1.0f / l_[reg];
  asm volatile("s_waitcnt lgkmcnt(0)" ::: "memory");
  float lv = arow[w * 16 + col];
  size_t obase = (size_t)(b * SEQ + qt * 64 + w * 16 + col) * 1024 + h * 64;
#pragma unroll
  for (int mt = 0; mt < 4; mt++) {
    short4v pk;
#pragma unroll
    for (int reg = 0; reg < 4; reg++) pk[reg] = (short)f2bf(oacc[mt][reg] * lv);
    *(short4v*)&o[obase + mt * 16 + quad * 4] = pk;
  }
}

// ---------------- launch ----------------
extern "C" void kernel_launch(void* const* d_in, const int* in_sizes, int n_in,
                              void* d_out, int out_size, void* d_ws, size_t ws_size,
                              hipStream_t stream) {
  const float* x_in    = (const float*)d_in[0];
  const float* rel_emb = (const float*)d_in[1];
  const float* qn_g    = (const float*)d_in[2];
  const float* wq      = (const float*)d_in[3];
  const float* wkv     = (const float*)d_in[4];
  const float* wo      = (const float*)d_in[5];
  const float* ln1_g   = (const float*)d_in[6];
  const float* w1      = (const float*)d_in[7];
  const float* convw   = (const float*)d_in[8];
  const float* ln2_g   = (const float*)d_in[9];
  const float* w2      = (const float*)d_in[10];
  const float* final_g = (const float*)d_in[11];
  float* out = (float*)d_out;

  // ws layout, no aliasing
  float* xbuf   = (float*)d_ws;                              // TOK*DIM f32
  float* bias_c = xbuf + (size_t)TOK * DIM;                  // 16*16*4096 f32
  ushort* hbuf  = (ushort*)(bias_c + (size_t)16 * 16 * 4096);
  ushort* obuf  = hbuf + (size_t)TOK * DIM;
  ushort* qkvbuf = obuf + (size_t)TOK * DIM;
  ushort* h1buf = qkvbuf + (size_t)TOK * QKVW;
  ushort* gbuf  = h1buf + (size_t)TOK * N1P;
  ushort* wtall = gbuf + (size_t)TOK * INNERP;

  size_t need = (size_t)((char*)(wtall + 6ull * LWT) - (char*)d_ws);
  bool big = ws_size >= need;   // ~188 MB: all-layer transposed weights resident

  bias_frag_kernel<<<256, 256, 0, stream>>>(rel_emb, bias_c);
  if (big)
    transpose_all<<<6 * TILES_PER_LAYER, 256, 0, stream>>>(wq, wkv, wo, w1, w2, wtall);

  for (int l = 0; l < DEPTH; l++) {
    // x*ALPHA + stop_grad(x)*(1-ALPHA) == x, so layer 0 reads x_in directly.
    const float* xres = (l == 0) ? x_in : xbuf;
    const ushort *wtq, *wto, *wt1, *wt2;
    if (big) {
      const ushort* bl = wtall + (size_t)l * LWT;
      wtq = bl; wto = bl + OFF_WO; wt1 = bl + OFF_W1; wt2 = bl + OFF_W2;
    } else {
      wtq = wto = wt1 = wt2 = wtall;
    }

    ln1024<ushort><<<TOK, 256, 0, stream>>>(xres, qn_g + l * DIM, hbuf);
    if (!big)
      transpose_qkv<<<dim3(18, 16), 256, 0, stream>>>(
          wq + (size_t)l * DIM * DIM, wkv + (size_t)l * DIM * 128, (ushort*)wtall);
    gemm_mfma64<false, ushort><<<dim3(18, 16), 256, 0, stream>>>(
        hbuf, wtq, nullptr, qkvbuf, QKVW, DIM, 1.0f);
    attn_mfma<<<dim3(BATCH * HEADS, 16), 256, 0, stream>>>(qkvbuf, bias_c, obuf);
    if (!big)
      transpose_vec<<<dim3(16, 16), 256, 0, stream>>>(
          wo + (size_t)l * DIM * DIM, (ushort*)wtall, DIM, DIM, DIM, DIM, 1.0f);
    gemm_mfma64<true, float><<<dim3(16, 16), 256, 0, stream>>>(
        obuf, wto, xres, xbuf, DIM, DIM, 1.0f);
    ln1024<ushort><<<TOK, 256, 0, stream>>>(xbuf, ln1_g + l * DIM, hbuf);
    if (!big)
      transpose_vec<<<dim3(86, 16), 256, 0, stream>>>(
          w1 + (size_t)l * DIM * INNER2, (ushort*)wtall, DIM, INNER2, DIM, N1P, 1.0f);
    gemm_mfma128<false, ushort><<<dim3(43, 16), 256, 0, stream>>>(
        hbuf, wt1, nullptr, h1buf, N1P, DIM, 1.0f);
    convglu_ln<<<TOK, 256, 0, stream>>>(
        h1buf, convw + (size_t)l * INNER2 * 3, ln2_g + l * INNER, gbuf);
    if (!big)
      transpose_vec<<<dim3(16, 43), 256, 0, stream>>>(
          w2 + (size_t)l * INNER * DIM, (ushort*)wtall, INNER, DIM, INNERP, DIM, 1.0f);
    gemm_mfma64<true, float><<<dim3(16, 16), 256, 0, stream>>>(
        gbuf, wt2, xbuf, xbuf, DIM, INNERP, 1.0f);
  }
  ln1024<float><<<TOK, 256, 0, stream>>>(xbuf, final_g, out);
}

// Round 3
// 1635.453 us; speedup vs baseline: 1.0231x; 1.0231x over previous
//
#include <hip/hip_runtime.h>
#include <math.h>

#define DEPTH 6
#define DIM 1024
#define HEADS 16
#define DH 64
#define INNER 2730
#define INNER2 5460
#define INNERP 2752      // INNER padded to 64
#define N1P 5504         // INNER2 padded to 128
#define BATCH 2
#define SEQ 1024
#define TOK (BATCH*SEQ)
#define QKVW 1152        // 1024 q + 64 k + 64 v

// per-layer transposed-weight layout (elems)
#define OFF_WO 1179648ull                  // after qkv (1152*1024)
#define OFF_W1 2228224ull                  // + wo (1024*1024)
#define OFF_W2 7864320ull                  // + w1 (5504*1024)
#define LWT    10682368ull                 // + w2 (1024*2752)
// 128k x 64n tiles: qkv 144 (128 wq + 16 wkv), wo 128, w1 688, w2 352
#define TILES_PER_LAYER 1312

typedef unsigned short ushort;
typedef __attribute__((ext_vector_type(8))) short short8;
typedef __attribute__((ext_vector_type(4))) short short4v;
typedef __attribute__((ext_vector_type(4))) unsigned short ushort4v;
typedef __attribute__((ext_vector_type(2))) unsigned short ushort2v;
typedef __attribute__((ext_vector_type(4))) float floatx4;

__device__ inline ushort f2bf(float f) {
  unsigned int u = __float_as_uint(f);
  u += 0x7FFF + ((u >> 16) & 1);
  return (ushort)(u >> 16);
}
__device__ inline float bf2f(ushort u) {
  return __uint_as_float(((unsigned int)u) << 16);
}

__device__ inline void gload_lds16(const ushort* g, ushort* l) {
  __builtin_amdgcn_global_load_lds(
      (const __attribute__((address_space(1))) unsigned int*)g,
      (__attribute__((address_space(3))) unsigned int*)l, 16, 0, 0);
}

// ---------------- bias fragment table ----------------
// bias_c[h][dq][rowgrp(16)][j(4)][col(16)][reg(4)]
__global__ void bias_frag_kernel(const float* __restrict__ rel_emb, float* __restrict__ bias_c) {
  int h = blockIdx.x >> 4, dq = blockIdx.x & 15;
  for (int i = threadIdx.x; i < 4096; i += 256) {
    int reg = i & 3, col = (i >> 2) & 15, j = (i >> 6) & 3, rowgrp = i >> 8;
    int row = rowgrp * 4 + reg, colg = j * 16 + col;
    int d = dq * 64 + row - colg;
    d = d < 0 ? 0 : (d > 1023 ? 1023 : d);
    int bucket;
    if (d < 16) {
      bucket = d;
    } else {
      float nf = (float)d;
      int vl = 16 + (int)(logf(nf / 16.0f) / 2.0794415416798357f * 16.0f);
      bucket = vl < 31 ? vl : 31;
    }
    bias_c[((size_t)(h * 16 + dq)) * 4096 + i] = rel_emb[bucket * HEADS + h];
  }
}

// ---------------- 64x64 transpose body (kept for !big fallback path) ----------------
__device__ inline void transpose_body(const float* __restrict__ W, ushort* __restrict__ Wt,
                                      int K, int N, int Kp, int Np, float scale,
                                      int k0, int n0, size_t dst_row0) {
  __shared__ float t[64][65];   // t[n][k]
  int tid = threadIdx.x;
  int kl = tid >> 4, nc = (tid & 15) * 4;
#pragma unroll
  for (int it = 0; it < 4; it++) {
    int k = kl + it * 16;
    int gk = k0 + k, gn = n0 + nc;
    floatx4 v = {0.f, 0.f, 0.f, 0.f};
    if (gk < K && gn < N) v = *(const floatx4*)&W[(size_t)gk * N + gn];
    t[nc + 0][k] = v[0] * scale;
    t[nc + 1][k] = v[1] * scale;
    t[nc + 2][k] = v[2] * scale;
    t[nc + 3][k] = v[3] * scale;
  }
  __syncthreads();
  int nr = tid >> 3, q = tid & 7;
#pragma unroll
  for (int it = 0; it < 2; it++) {
    int n = nr + it * 32;
    if (n0 + n < Np) {
      short8 p;
#pragma unroll
      for (int e = 0; e < 8; e++) p[e] = (short)f2bf(t[n][q * 8 + e]);
      *(short8*)&Wt[(dst_row0 + n) * Kp + k0 + q * 8] = p;
    }
  }
}

__global__ __launch_bounds__(256) void transpose_vec(const float* __restrict__ W,
                                                     ushort* __restrict__ Wt,
                                                     int K, int N, int Kp, int Np, float scale) {
  transpose_body(W, Wt, K, N, Kp, Np, scale, blockIdx.y * 64, blockIdx.x * 64,
                 (size_t)blockIdx.x * 64);
}

// fused wq (scaled) + wkv transpose into one [1152 x 1024] buffer. grid (18,16)
__global__ __launch_bounds__(256) void transpose_qkv(const float* __restrict__ wq,
                                                     const float* __restrict__ wkv,
                                                     ushort* __restrict__ Wt) {
  int bx = blockIdx.x;
  if (bx < 16) {
    transpose_body(wq, Wt, 1024, 1024, 1024, 1024, 0.125f, blockIdx.y * 64, bx * 64,
                   (size_t)bx * 64);
  } else {
    transpose_body(wkv, Wt, 1024, 128, 1024, 128, 1.0f, blockIdx.y * 64, (bx - 16) * 64,
                   (size_t)1024 + (bx - 16) * 64);
  }
}

// ---------------- 128k x 64n transpose body: 256B read segs, 256B write segs ----------------
__device__ inline void transpose_body128(const float* __restrict__ W, ushort* __restrict__ Wt,
                                         int K, int N, int Kp, int Np, float scale,
                                         int k0, int n0, size_t dst_row0) {
  __shared__ float t[64][129];   // t[n][k]; bank=(n+k)%32 -> ~2-way on scattered writes
  int tid = threadIdx.x;
  int kl = tid >> 4, nc = (tid & 15) * 4;
#pragma unroll
  for (int it = 0; it < 8; it++) {
    int k = kl + it * 16;
    int gk = k0 + k, gn = n0 + nc;
    floatx4 v = {0.f, 0.f, 0.f, 0.f};
    if (gk < K && gn < N) v = *(const floatx4*)&W[(size_t)gk * N + gn];
    t[nc + 0][k] = v[0] * scale;
    t[nc + 1][k] = v[1] * scale;
    t[nc + 2][k] = v[2] * scale;
    t[nc + 3][k] = v[3] * scale;
  }
  __syncthreads();
  int nr = tid >> 3, q = tid & 7;
#pragma unroll
  for (int p = 0; p < 2; p++) {
    int n = nr + p * 32;
    if (n0 + n < Np) {
      size_t rbase = (dst_row0 + n) * (size_t)Kp + k0;
#pragma unroll
      for (int it8 = 0; it8 < 2; it8++) {
        int k = it8 * 64 + q * 8;
        if (k0 + k < Kp) {
          short8 pk;
#pragma unroll
          for (int e = 0; e < 8; e++) pk[e] = (short)f2bf(t[n][k + e]);
          *(short8*)&Wt[rbase + k] = pk;
        }
      }
    }
  }
}

// all-layer batched weight transpose, 128x64 tiles. grid: 6*TILES_PER_LAYER
__global__ __launch_bounds__(256) void transpose_all(const float* __restrict__ wq,
                                                     const float* __restrict__ wkv,
                                                     const float* __restrict__ wo,
                                                     const float* __restrict__ w1,
                                                     const float* __restrict__ w2,
                                                     ushort* __restrict__ wtall) {
  int t = blockIdx.x;
  int l = t / TILES_PER_LAYER, r = t % TILES_PER_LAYER;
  ushort* base = wtall + (size_t)l * LWT;
  if (r < 144) {                        // qkv
    if (r < 128) {                      // wq: 16 n-tiles x 8 k-tiles
      int bx = r & 15, by = r >> 4;
      transpose_body128(wq + (size_t)l * 1024 * 1024, base, 1024, 1024, 1024, 1024,
                        0.125f, by * 128, bx * 64, (size_t)bx * 64);
    } else {                            // wkv: 2 n-tiles x 8 k-tiles
      int q = r - 128, bx = q & 1, by = q >> 1;
      transpose_body128(wkv + (size_t)l * 1024 * 128, base, 1024, 128, 1024, 128,
                        1.0f, by * 128, bx * 64, 1024 + (size_t)bx * 64);
    }
  } else if (r < 272) {                 // wo: 16 x 8
    int q = r - 144, bx = q & 15, by = q >> 4;
    transpose_body128(wo + (size_t)l * 1024 * 1024, base + OFF_WO, 1024, 1024, 1024, 1024,
                      1.0f, by * 128, bx * 64, (size_t)bx * 64);
  } else if (r < 960) {                 // w1: 86 x 8
    int q = r - 272, bx = q % 86, by = q / 86;
    transpose_body128(w1 + (size_t)l * 1024 * 5460, base + OFF_W1, 1024, 5460, 1024, 5504,
                      1.0f, by * 128, bx * 64, (size_t)bx * 64);
  } else {                              // w2: 16 x 22
    int q = r - 960, bx = q & 15, by = q >> 4;
    transpose_body128(w2 + (size_t)l * 2730 * 1024, base + OFF_W2, 2730, 1024, 2752, 1024,
                      1.0f, by * 128, bx * 64, (size_t)bx * 64);
  }
}

// ---------------- LayerNorm specialized for 1024 cols ----------------
template <typename OutT>
__global__ __launch_bounds__(256) void ln1024(const float* __restrict__ in,
                                              const float* __restrict__ g,
                                              OutT* __restrict__ out) {
  int row = blockIdx.x;
  int tid = threadIdx.x;
  floatx4 v = *(const floatx4*)&in[(size_t)row * 1024 + tid * 4];
  float s = v[0] + v[1] + v[2] + v[3];
  float ss = v[0] * v[0] + v[1] * v[1] + v[2] * v[2] + v[3] * v[3];
#pragma unroll
  for (int off = 32; off; off >>= 1) {
    s  += __shfl_down(s, off, 64);
    ss += __shfl_down(ss, off, 64);
  }
  __shared__ float l1[4], l2[4];
  int wid = tid >> 6, lane = tid & 63;
  if (lane == 0) { l1[wid] = s; l2[wid] = ss; }
  __syncthreads();
  if (tid == 0) {
    float a = l1[0] + l1[1] + l1[2] + l1[3];
    float bb = l2[0] + l2[1] + l2[2] + l2[3];
    float m = a * (1.0f / 1024.0f);
    float var = bb * (1.0f / 1024.0f) - m * m;
    l1[0] = m;
    l2[0] = rsqrtf(var + 1e-5f);
  }
  __syncthreads();
  float m = l1[0], r = l2[0];
  floatx4 gv = *(const floatx4*)&g[tid * 4];
  if constexpr (sizeof(OutT) == 2) {
    short4v p;
#pragma unroll
    for (int e = 0; e < 4; e++) p[e] = (short)f2bf((v[e] - m) * r * gv[e]);
    *(short4v*)&out[(size_t)row * 1024 + tid * 4] = p;
  } else {
    floatx4 p;
#pragma unroll
    for (int e = 0; e < 4; e++) p[e] = (v[e] - m) * r * gv[e];
    *(floatx4*)&out[(size_t)row * 1024 + tid * 4] = p;
  }
}

// ---------------- bf16 MFMA GEMM, 128x128 tile ----------------
template <bool ADD, typename OutT>
__global__ __launch_bounds__(256) void gemm_mfma128(const ushort* __restrict__ A,
                                                    const ushort* __restrict__ Bt,
                                                    const float* __restrict__ Cin,
                                                    OutT* __restrict__ C,
                                                    int N, int K, float scale) {
  __shared__ ushort Als[128 * 64];
  __shared__ ushort Bls[128 * 64];
  int tid = threadIdx.x;
  int w = tid >> 6, lane = tid & 63;
  int wr = w >> 1, wc = w & 1;
  size_t row0 = (size_t)blockIdx.y * 128, col0 = (size_t)blockIdx.x * 128;

  const ushort* Ag = A + (row0 + w * 32 + (lane >> 3)) * (size_t)K + (lane & 7) * 8;
  const ushort* Bg = Bt + (col0 + w * 32 + (lane >> 3)) * (size_t)K + (lane & 7) * 8;
  ushort* Al = Als + w * 32 * 64;
  ushort* Bl = Bls + w * 32 * 64;

  floatx4 acc[4][4];
#pragma unroll
  for (int i = 0; i < 4; i++)
#pragma unroll
    for (int j = 0; j < 4; j++) { floatx4 z = {0.f, 0.f, 0.f, 0.f}; acc[i][j] = z; }

  int mrow = lane & 15, kq = (lane >> 4) * 8;
  for (int k0 = 0; k0 < K; k0 += 64) {
#pragma unroll
    for (int r = 0; r < 4; r++) {
      gload_lds16(Ag + (size_t)(r * 8) * K + k0, Al + r * 8 * 64);
      gload_lds16(Bg + (size_t)(r * 8) * K + k0, Bl + r * 8 * 64);
    }
    __syncthreads();
#pragma unroll
    for (int kk = 0; kk < 64; kk += 32) {
      short8 a[4], b[4];
#pragma unroll
      for (int i = 0; i < 4; i++)
        a[i] = *(const short8*)&Als[(wr * 64 + i * 16 + mrow) * 64 + kk + kq];
#pragma unroll
      for (int j = 0; j < 4; j++)
        b[j] = *(const short8*)&Bls[(wc * 64 + j * 16 + mrow) * 64 + kk + kq];
#pragma unroll
      for (int i = 0; i < 4; i++)
#pragma unroll
        for (int j = 0; j < 4; j++)
          acc[i][j] = __builtin_amdgcn_mfma_f32_16x16x32_bf16(a[i], b[j], acc[i][j], 0, 0, 0);
    }
    __syncthreads();
  }
  int orow = (lane >> 4) * 4, ocol = lane & 15;
#pragma unroll
  for (int i = 0; i < 4; i++) {
#pragma unroll
    for (int ii = 0; ii < 4; ii++) {
      size_t gr = row0 + wr * 64 + i * 16 + orow + ii;
#pragma unroll
      for (int j = 0; j < 4; j++) {
        size_t gc = col0 + wc * 64 + j * 16 + ocol;
        float v = acc[i][j][ii] * scale;
        if (ADD) v += Cin[gr * N + gc];
        if constexpr (sizeof(OutT) == 2) C[gr * N + gc] = f2bf(v);
        else C[gr * N + gc] = v;
      }
    }
  }
}

// ---------------- bf16 MFMA GEMM, 64x64 tile (2x blocks/CU for small grids) ----------------
// 4 waves; wave w owns all 64 rows x cols [w*16, w*16+16).
template <bool ADD, typename OutT>
__global__ __launch_bounds__(256) void gemm64x64(const ushort* __restrict__ A,
                                                 const ushort* __restrict__ Bt,
                                                 const float* __restrict__ Cin,
                                                 OutT* __restrict__ C,
                                                 int N, int K, float scale) {
  __shared__ ushort Als[64 * 64];
  __shared__ ushort Bls[64 * 64];
  int tid = threadIdx.x;
  int w = tid >> 6, lane = tid & 63;
  size_t row0 = (size_t)blockIdx.y * 64, col0 = (size_t)blockIdx.x * 64;

  // staging: rows (tid>>3) + p*32, 16B chunk (tid&7); lane-linear LDS dest.
  const ushort* Ag = A + (row0 + (tid >> 3)) * (size_t)K + (tid & 7) * 8;
  const ushort* Bg = Bt + (col0 + (tid >> 3)) * (size_t)K + (tid & 7) * 8;
  ushort* Al = Als + (tid >> 3) * 64 + (tid & 7) * 8;
  ushort* Bl = Bls + (tid >> 3) * 64 + (tid & 7) * 8;

  floatx4 acc[4];
#pragma unroll
  for (int i = 0; i < 4; i++) { floatx4 z = {0.f, 0.f, 0.f, 0.f}; acc[i] = z; }

  int mrow = lane & 15, kq = (lane >> 4) * 8;
  for (int k0 = 0; k0 < K; k0 += 64) {
#pragma unroll
    for (int p = 0; p < 2; p++) {
      gload_lds16(Ag + (size_t)(p * 32) * K + k0, Al + p * 32 * 64);
      gload_lds16(Bg + (size_t)(p * 32) * K + k0, Bl + p * 32 * 64);
    }
    __syncthreads();
#pragma unroll
    for (int kk = 0; kk < 64; kk += 32) {
      short8 b = *(const short8*)&Bls[(w * 16 + mrow) * 64 + kk + kq];
#pragma unroll
      for (int i = 0; i < 4; i++) {
        short8 a = *(const short8*)&Als[(i * 16 + mrow) * 64 + kk + kq];
        acc[i] = __builtin_amdgcn_mfma_f32_16x16x32_bf16(a, b, acc[i], 0, 0, 0);
      }
    }
    __syncthreads();
  }
  int orow = (lane >> 4) * 4, ocol = lane & 15;
#pragma unroll
  for (int i = 0; i < 4; i++) {
#pragma unroll
    for (int ii = 0; ii < 4; ii++) {
      size_t gr = row0 + i * 16 + orow + ii;
      size_t gc = col0 + w * 16 + ocol;
      float v = acc[i][ii] * scale;
      if (ADD) v += Cin[gr * N + gc];
      if constexpr (sizeof(OutT) == 2) C[gr * N + gc] = f2bf(v);
      else C[gr * N + gc] = v;
    }
  }
}

// ---------------- fused causal conv(3) + GLU(gelu exact) + LayerNorm -> bf16 padded ----------------
__global__ __launch_bounds__(256) void convglu_ln(const ushort* __restrict__ h1,
                                                  const float* __restrict__ cw,
                                                  const float* __restrict__ lng,
                                                  ushort* __restrict__ out) {
  int t = blockIdx.x;
  int n = t & (SEQ - 1);
  int tid = threadIdx.x;
  const ushort* r0 = h1 + (size_t)t * N1P;
  float vals[3][4];
  float s = 0.f, ss = 0.f;
#pragma unroll
  for (int it = 0; it < 3; it++) {
    int c = (it * 256 + tid) * 4;
#pragma unroll
    for (int e = 0; e < 4; e++) vals[it][e] = 0.f;
    if (c < INNER) {
      ushort4v a2 = *(const ushort4v*)&r0[c];
      ushort4v a1 = {0, 0, 0, 0}, a0 = {0, 0, 0, 0};
      if (n >= 1) a1 = *(const ushort4v*)&r0[c - N1P];
      if (n >= 2) a0 = *(const ushort4v*)&r0[c - 2 * N1P];
      int cg = c + INNER;   // ≡ 2 mod 4 -> two 4B-aligned ushort2 loads per row
      ushort2v g2a = *(const ushort2v*)&r0[cg];
      ushort2v g2b = *(const ushort2v*)&r0[cg + 2];
      ushort2v g1a = {0, 0}, g1b = {0, 0}, g0a = {0, 0}, g0b = {0, 0};
      if (n >= 1) { g1a = *(const ushort2v*)&r0[cg - N1P]; g1b = *(const ushort2v*)&r0[cg + 2 - N1P]; }
      if (n >= 2) { g0a = *(const ushort2v*)&r0[cg - 2 * N1P]; g0b = *(const ushort2v*)&r0[cg + 2 - 2 * N1P]; }
      const floatx4* cwa = (const floatx4*)(cw + (size_t)c * 3);
      floatx4 f0 = cwa[0], f1 = cwa[1], f2 = cwa[2];
      float wa[12] = {f0[0], f0[1], f0[2], f0[3], f1[0], f1[1], f1[2], f1[3],
                      f2[0], f2[1], f2[2], f2[3]};
#pragma unroll
      for (int e = 0; e < 4; e++) {
        int ce = c + e;
        if (ce < INNER) {
          float av = bf2f(a0[e]) * wa[e * 3] + bf2f(a1[e]) * wa[e * 3 + 1] +
                     bf2f(a2[e]) * wa[e * 3 + 2];
          int cge = ce + INNER;
          float w0g = cw[cge * 3], w1g = cw[cge * 3 + 1], w2g = cw[cge * 3 + 2];
          float g0f = bf2f(e < 2 ? g0a[e & 1] : g0b[e & 1]);
          float g1f = bf2f(e < 2 ? g1a[e & 1] : g1b[e & 1]);
          float g2f = bf2f(e < 2 ? g2a[e & 1] : g2b[e & 1]);
          float gvv = g0f * w0g + g1f * w1g + g2f * w2g;
          float gl = 0.5f * gvv * (1.0f + erff(gvv * 0.70710678118654752f));
          float val = gl * av;
          vals[it][e] = val;
          s += val;
          ss += val * val;
        }
      }
    }
  }
#pragma unroll
  for (int off = 32; off; off >>= 1) {
    s  += __shfl_down(s, off, 64);
    ss += __shfl_down(ss, off, 64);
  }
  __shared__ float l1[4], l2[4];
  int wid = tid >> 6, lane = tid & 63;
  if (lane == 0) { l1[wid] = s; l2[wid] = ss; }
  __syncthreads();
  if (tid == 0) {
    float a = l1[0] + l1[1] + l1[2] + l1[3];
    float bb = l2[0] + l2[1] + l2[2] + l2[3];
    float m = a * (1.0f / INNER);
    float var = bb * (1.0f / INNER) - m * m;
    l1[0] = m;
    l2[0] = rsqrtf(var + 1e-5f);
  }
  __syncthreads();
  float m = l1[0], r = l2[0];
#pragma unroll
  for (int it = 0; it < 3; it++) {
    int c = (it * 256 + tid) * 4;
    if (c < INNERP) {
      short4v p;
#pragma unroll
      for (int e = 0; e < 4; e++) {
        int ce = c + e;
        p[e] = (ce < INNER) ? (short)f2bf((vals[it][e] - m) * r * lng[ce]) : (short)0;
      }
      *(short4v*)&out[(size_t)t * INNERP + c] = p;
    }
  }
}

// ---------------- MFMA flash attention ----------------
__global__ __launch_bounds__(256) void attn_mfma(const ushort* __restrict__ qkv,
                                                 const float* __restrict__ bias_c,
                                                 ushort* __restrict__ o) {
  __shared__ ushort Ks[64 * 72];
  __shared__ ushort Vt[64 * 72];
  __shared__ ushort Ps[64 * 72];
  __shared__ float arow[64];
  int tid = threadIdx.x;
  int lane = tid & 63, w = tid >> 6;
  int quad = lane >> 4, col = lane & 15;
  int b = blockIdx.x >> 4, h = blockIdx.x & 15;
  int y = blockIdx.y;
  int qt = (y < 8) ? (15 - y) : (y - 8);

  const ushort* qrow = qkv + (size_t)(b * SEQ + qt * 64 + w * 16 + col) * QKVW + h * 64;
  short8 qa[2];
  qa[0] = *(const short8*)&qrow[quad * 8];
  qa[1] = *(const short8*)&qrow[32 + quad * 8];

  float m_[4], l_[4];
  floatx4 oacc[4];
#pragma unroll
  for (int r = 0; r < 4; r++) { m_[r] = -1e30f; l_[r] = 0.f; }
#pragma unroll
  for (int mt = 0; mt < 4; mt++) { floatx4 z = {0.f, 0.f, 0.f, 0.f}; oacc[mt] = z; }

  for (int kc = 0; kc <= qt; kc++) {
    const ushort* kvb = qkv + (size_t)(b * SEQ + kc * 64) * QKVW;
#pragma unroll
    for (int it = 0; it < 2; it++) {
      int r = lane;
      int c8 = w + it * 4;
      short8 kk8 = *(const short8*)&kvb[(size_t)r * QKVW + 1024 + c8 * 8];
      *(short8*)&Ks[r * 72 + c8 * 8] = kk8;
      short8 vv = *(const short8*)&kvb[(size_t)r * QKVW + 1088 + c8 * 8];
#pragma unroll
      for (int e = 0; e < 8; e++) Vt[(c8 * 8 + e) * 72 + r] = (ushort)vv[e];
    }
    __syncthreads();

    floatx4 sarr[4];
#pragma unroll
    for (int j = 0; j < 4; j++) { floatx4 z = {0.f, 0.f, 0.f, 0.f}; sarr[j] = z; }
#pragma unroll
    for (int kk = 0; kk < 2; kk++) {
#pragma unroll
      for (int j = 0; j < 4; j++) {
        short8 kb = *(const short8*)&Ks[(j * 16 + col) * 72 + kk * 32 + quad * 8];
        sarr[j] = __builtin_amdgcn_mfma_f32_16x16x32_bf16(qa[kk], kb, sarr[j], 0, 0, 0);
      }
    }

    int dq = qt - kc;
    const floatx4* bc = (const floatx4*)(bias_c + ((size_t)(h * 16 + dq) * 4096 + (w * 4 + quad) * 256));
    float pv[4][4];
#pragma unroll
    for (int j = 0; j < 4; j++) {
      floatx4 bf = bc[j * 16 + col];
#pragma unroll
      for (int reg = 0; reg < 4; reg++) {
        float v = sarr[j][reg] + bf[reg];
        if (dq == 0 && (j * 16 + col) > (w * 16 + quad * 4 + reg)) v = -1e30f;
        pv[j][reg] = v;
      }
    }

#pragma unroll
    for (int reg = 0; reg < 4; reg++) {
      float cm = fmaxf(fmaxf(pv[0][reg], pv[1][reg]), fmaxf(pv[2][reg], pv[3][reg]));
      cm = fmaxf(cm, __shfl_xor(cm, 1, 64));
      cm = fmaxf(cm, __shfl_xor(cm, 2, 64));
      cm = fmaxf(cm, __shfl_xor(cm, 4, 64));
      cm = fmaxf(cm, __shfl_xor(cm, 8, 64));
      float nm = fmaxf(m_[reg], cm);
      float alpha = __expf(m_[reg] - nm);
      float rs = 0.f;
#pragma unroll
      for (int j = 0; j < 4; j++) {
        float e = __expf(pv[j][reg] - nm);
        pv[j][reg] = e;
        rs += e;
      }
      rs += __shfl_xor(rs, 1, 64);
      rs += __shfl_xor(rs, 2, 64);
      rs += __shfl_xor(rs, 4, 64);
      rs += __shfl_xor(rs, 8, 64);
      l_[reg] = l_[reg] * alpha + rs;
      m_[reg] = nm;
      if (col == 0) arow[w * 16 + quad * 4 + reg] = alpha;
    }

#pragma unroll
    for (int j = 0; j < 4; j++)
#pragma unroll
      for (int reg = 0; reg < 4; reg++)
        Ps[(w * 16 + quad * 4 + reg) * 72 + j * 16 + col] = f2bf(pv[j][reg]);

    asm volatile("s_waitcnt lgkmcnt(0)" ::: "memory");
    float aval = arow[w * 16 + col];
#pragma unroll
    for (int mt = 0; mt < 4; mt++) oacc[mt] *= aval;

#pragma unroll
    for (int kk = 0; kk < 2; kk++) {
      short8 pb = *(const short8*)&Ps[(w * 16 + col) * 72 + kk * 32 + quad * 8];
#pragma unroll
      for (int mt = 0; mt < 4; mt++) {
        short8 va = *(const short8*)&Vt[(mt * 16 + col) * 72 + kk * 32 + quad * 8];
        oacc[mt] = __builtin_amdgcn_mfma_f32_16x16x32_bf16(va, pb, oacc[mt], 0, 0, 0);
      }
    }
    __syncthreads();
  }

#pragma unroll
  for (int reg = 0; reg < 4; reg++)
    if (col == 0) arow[w * 16 + quad * 4 + reg] = 1.0f / l_[reg];
  asm volatile("s_waitcnt lgkmcnt(0)" ::: "memory");
  float lv = arow[w * 16 + col];
  size_t obase = (size_t)(b * SEQ + qt * 64 + w * 16 + col) * 1024 + h * 64;
#pragma unroll
  for (int mt = 0; mt < 4; mt++) {
    short4v pk;
#pragma unroll
    for (int reg = 0; reg < 4; reg++) pk[reg] = (short)f2bf(oacc[mt][reg] * lv);
    *(short4v*)&o[obase + mt * 16 + quad * 4] = pk;
  }
}

// ---------------- launch ----------------
extern "C" void kernel_launch(void* const* d_in, const int* in_sizes, int n_in,
                              void* d_out, int out_size, void* d_ws, size_t ws_size,
                              hipStream_t stream) {
  const float* x_in    = (const float*)d_in[0];
  const float* rel_emb = (const float*)d_in[1];
  const float* qn_g    = (const float*)d_in[2];
  const float* wq      = (const float*)d_in[3];
  const float* wkv     = (const float*)d_in[4];
  const float* wo      = (const float*)d_in[5];
  const float* ln1_g   = (const float*)d_in[6];
  const float* w1      = (const float*)d_in[7];
  const float* convw   = (const float*)d_in[8];
  const float* ln2_g   = (const float*)d_in[9];
  const float* w2      = (const float*)d_in[10];
  const float* final_g = (const float*)d_in[11];
  float* out = (float*)d_out;

  // ws layout, no aliasing
  float* xbuf   = (float*)d_ws;                              // TOK*DIM f32
  float* bias_c = xbuf + (size_t)TOK * DIM;                  // 16*16*4096 f32
  ushort* hbuf  = (ushort*)(bias_c + (size_t)16 * 16 * 4096);
  ushort* obuf  = hbuf + (size_t)TOK * DIM;
  ushort* qkvbuf = obuf + (size_t)TOK * DIM;
  ushort* h1buf = qkvbuf + (size_t)TOK * QKVW;
  ushort* gbuf  = h1buf + (size_t)TOK * N1P;
  ushort* wtall = gbuf + (size_t)TOK * INNERP;

  size_t need = (size_t)((char*)(wtall + 6ull * LWT) - (char*)d_ws);
  bool big = ws_size >= need;   // ~188 MB: all-layer transposed weights resident

  bias_frag_kernel<<<256, 256, 0, stream>>>(rel_emb, bias_c);
  if (big)
    transpose_all<<<6 * TILES_PER_LAYER, 256, 0, stream>>>(wq, wkv, wo, w1, w2, wtall);

  for (int l = 0; l < DEPTH; l++) {
    // x*ALPHA + stop_grad(x)*(1-ALPHA) == x, so layer 0 reads x_in directly.
    const float* xres = (l == 0) ? x_in : xbuf;
    const ushort *wtq, *wto, *wt1, *wt2;
    if (big) {
      const ushort* bl = wtall + (size_t)l * LWT;
      wtq = bl; wto = bl + OFF_WO; wt1 = bl + OFF_W1; wt2 = bl + OFF_W2;
    } else {
      wtq = wto = wt1 = wt2 = wtall;
    }

    ln1024<ushort><<<TOK, 256, 0, stream>>>(xres, qn_g + l * DIM, hbuf);
    if (!big)
      transpose_qkv<<<dim3(18, 16), 256, 0, stream>>>(
          wq + (size_t)l * DIM * DIM, wkv + (size_t)l * DIM * 128, (ushort*)wtall);
    gemm64x64<false, ushort><<<dim3(18, 32), 256, 0, stream>>>(
        hbuf, wtq, nullptr, qkvbuf, QKVW, DIM, 1.0f);
    attn_mfma<<<dim3(BATCH * HEADS, 16), 256, 0, stream>>>(qkvbuf, bias_c, obuf);
    if (!big)
      transpose_vec<<<dim3(16, 16), 256, 0, stream>>>(
          wo + (size_t)l * DIM * DIM, (ushort*)wtall, DIM, DIM, DIM, DIM, 1.0f);
    gemm64x64<true, float><<<dim3(16, 32), 256, 0, stream>>>(
        obuf, wto, xres, xbuf, DIM, DIM, 1.0f);
    ln1024<ushort><<<TOK, 256, 0, stream>>>(xbuf, ln1_g + l * DIM, hbuf);
    if (!big)
      transpose_vec<<<dim3(86, 16), 256, 0, stream>>>(
          w1 + (size_t)l * DIM * INNER2, (ushort*)wtall, DIM, INNER2, DIM, N1P, 1.0f);
    gemm_mfma128<false, ushort><<<dim3(43, 16), 256, 0, stream>>>(
        hbuf, wt1, nullptr, h1buf, N1P, DIM, 1.0f);
    convglu_ln<<<TOK, 256, 0, stream>>>(
        h1buf, convw + (size_t)l * INNER2 * 3, ln2_g + l * INNER, gbuf);
    if (!big)
      transpose_vec<<<dim3(16, 43), 256, 0, stream>>>(
          w2 + (size_t)l * INNER * DIM, (ushort*)wtall, INNER, DIM, INNERP, DIM, 1.0f);
    gemm64x64<true, float><<<dim3(16, 32), 256, 0, stream>>>(
        gbuf, wt2, xbuf, xbuf, DIM, INNERP, 1.0f);
  }
  ln1024<float><<<TOK, 256, 0, stream>>>(xbuf, final_g, out);
}

// Round 4
// 1553.285 us; speedup vs baseline: 1.0772x; 1.0529x over previous
//
#include <hip/hip_runtime.h>
#include <math.h>

#define DEPTH 6
#define DIM 1024
#define HEADS 16
#define DH 64
#define INNER 2730
#define INNER2 5460
#define INNERP 2752      // INNER padded to 64
#define N1P 5504         // INNER2 padded to 128
#define BATCH 2
#define SEQ 1024
#define TOK (BATCH*SEQ)
#define QKVW 1152        // 1024 q + 64 k + 64 v

// per-layer transposed-weight layout (elems)
#define OFF_WO 1179648ull                  // after qkv (1152*1024)
#define OFF_W1 2228224ull                  // + wo (1024*1024)
#define OFF_W2 7864320ull                  // + w1 (5504*1024)
#define LWT    10682368ull                 // + w2 (1024*2752)
// 128k x 64n tiles: qkv 144 (128 wq + 16 wkv), wo 128, w1 688, w2 352
#define TILES_PER_LAYER 1312

#define VMCNT(n) asm volatile("s_waitcnt vmcnt(" #n ")" ::: "memory")

typedef unsigned short ushort;
typedef __attribute__((ext_vector_type(8))) short short8;
typedef __attribute__((ext_vector_type(4))) short short4v;
typedef __attribute__((ext_vector_type(4))) unsigned short ushort4v;
typedef __attribute__((ext_vector_type(2))) unsigned short ushort2v;
typedef __attribute__((ext_vector_type(4))) float floatx4;

__device__ inline ushort f2bf(float f) {
  unsigned int u = __float_as_uint(f);
  u += 0x7FFF + ((u >> 16) & 1);
  return (ushort)(u >> 16);
}
__device__ inline float bf2f(ushort u) {
  return __uint_as_float(((unsigned int)u) << 16);
}

__device__ inline void gload_lds16(const ushort* g, ushort* l) {
  __builtin_amdgcn_global_load_lds(
      (const __attribute__((address_space(1))) unsigned int*)g,
      (__attribute__((address_space(3))) unsigned int*)l, 16, 0, 0);
}

// ---------------- bias fragment table ----------------
// bias_c[h][dq][rowgrp(16)][j(4)][col(16)][reg(4)]
__global__ void bias_frag_kernel(const float* __restrict__ rel_emb, float* __restrict__ bias_c) {
  int h = blockIdx.x >> 4, dq = blockIdx.x & 15;
  for (int i = threadIdx.x; i < 4096; i += 256) {
    int reg = i & 3, col = (i >> 2) & 15, j = (i >> 6) & 3, rowgrp = i >> 8;
    int row = rowgrp * 4 + reg, colg = j * 16 + col;
    int d = dq * 64 + row - colg;
    d = d < 0 ? 0 : (d > 1023 ? 1023 : d);
    int bucket;
    if (d < 16) {
      bucket = d;
    } else {
      float nf = (float)d;
      int vl = 16 + (int)(logf(nf / 16.0f) / 2.0794415416798357f * 16.0f);
      bucket = vl < 31 ? vl : 31;
    }
    bias_c[((size_t)(h * 16 + dq)) * 4096 + i] = rel_emb[bucket * HEADS + h];
  }
}

// ---------------- 64x64 transpose body (kept for !big fallback path) ----------------
__device__ inline void transpose_body(const float* __restrict__ W, ushort* __restrict__ Wt,
                                      int K, int N, int Kp, int Np, float scale,
                                      int k0, int n0, size_t dst_row0) {
  __shared__ float t[64][65];   // t[n][k]
  int tid = threadIdx.x;
  int kl = tid >> 4, nc = (tid & 15) * 4;
#pragma unroll
  for (int it = 0; it < 4; it++) {
    int k = kl + it * 16;
    int gk = k0 + k, gn = n0 + nc;
    floatx4 v = {0.f, 0.f, 0.f, 0.f};
    if (gk < K && gn < N) v = *(const floatx4*)&W[(size_t)gk * N + gn];
    t[nc + 0][k] = v[0] * scale;
    t[nc + 1][k] = v[1] * scale;
    t[nc + 2][k] = v[2] * scale;
    t[nc + 3][k] = v[3] * scale;
  }
  __syncthreads();
  int nr = tid >> 3, q = tid & 7;
#pragma unroll
  for (int it = 0; it < 2; it++) {
    int n = nr + it * 32;
    if (n0 + n < Np) {
      short8 p;
#pragma unroll
      for (int e = 0; e < 8; e++) p[e] = (short)f2bf(t[n][q * 8 + e]);
      *(short8*)&Wt[(dst_row0 + n) * Kp + k0 + q * 8] = p;
    }
  }
}

__global__ __launch_bounds__(256) void transpose_vec(const float* __restrict__ W,
                                                     ushort* __restrict__ Wt,
                                                     int K, int N, int Kp, int Np, float scale) {
  transpose_body(W, Wt, K, N, Kp, Np, scale, blockIdx.y * 64, blockIdx.x * 64,
                 (size_t)blockIdx.x * 64);
}

// fused wq (scaled) + wkv transpose into one [1152 x 1024] buffer. grid (18,16)
__global__ __launch_bounds__(256) void transpose_qkv(const float* __restrict__ wq,
                                                     const float* __restrict__ wkv,
                                                     ushort* __restrict__ Wt) {
  int bx = blockIdx.x;
  if (bx < 16) {
    transpose_body(wq, Wt, 1024, 1024, 1024, 1024, 0.125f, blockIdx.y * 64, bx * 64,
                   (size_t)bx * 64);
  } else {
    transpose_body(wkv, Wt, 1024, 128, 1024, 128, 1.0f, blockIdx.y * 64, (bx - 16) * 64,
                   (size_t)1024 + (bx - 16) * 64);
  }
}

// ---------------- 128k x 64n transpose body ----------------
__device__ inline void transpose_body128(const float* __restrict__ W, ushort* __restrict__ Wt,
                                         int K, int N, int Kp, int Np, float scale,
                                         int k0, int n0, size_t dst_row0) {
  __shared__ float t[64][129];   // t[n][k]
  int tid = threadIdx.x;
  int kl = tid >> 4, nc = (tid & 15) * 4;
#pragma unroll
  for (int it = 0; it < 8; it++) {
    int k = kl + it * 16;
    int gk = k0 + k, gn = n0 + nc;
    floatx4 v = {0.f, 0.f, 0.f, 0.f};
    if (gk < K && gn < N) v = *(const floatx4*)&W[(size_t)gk * N + gn];
    t[nc + 0][k] = v[0] * scale;
    t[nc + 1][k] = v[1] * scale;
    t[nc + 2][k] = v[2] * scale;
    t[nc + 3][k] = v[3] * scale;
  }
  __syncthreads();
  int nr = tid >> 3, q = tid & 7;
#pragma unroll
  for (int p = 0; p < 2; p++) {
    int n = nr + p * 32;
    if (n0 + n < Np) {
      size_t rbase = (dst_row0 + n) * (size_t)Kp + k0;
#pragma unroll
      for (int it8 = 0; it8 < 2; it8++) {
        int k = it8 * 64 + q * 8;
        if (k0 + k < Kp) {
          short8 pk;
#pragma unroll
          for (int e = 0; e < 8; e++) pk[e] = (short)f2bf(t[n][k + e]);
          *(short8*)&Wt[rbase + k] = pk;
        }
      }
    }
  }
}

// all-layer batched weight transpose, 128x64 tiles. grid: 6*TILES_PER_LAYER
__global__ __launch_bounds__(256) void transpose_all(const float* __restrict__ wq,
                                                     const float* __restrict__ wkv,
                                                     const float* __restrict__ wo,
                                                     const float* __restrict__ w1,
                                                     const float* __restrict__ w2,
                                                     ushort* __restrict__ wtall) {
  int t = blockIdx.x;
  int l = t / TILES_PER_LAYER, r = t % TILES_PER_LAYER;
  ushort* base = wtall + (size_t)l * LWT;
  if (r < 144) {                        // qkv
    if (r < 128) {                      // wq: 16 n-tiles x 8 k-tiles
      int bx = r & 15, by = r >> 4;
      transpose_body128(wq + (size_t)l * 1024 * 1024, base, 1024, 1024, 1024, 1024,
                        0.125f, by * 128, bx * 64, (size_t)bx * 64);
    } else {                            // wkv: 2 n-tiles x 8 k-tiles
      int q = r - 128, bx = q & 1, by = q >> 1;
      transpose_body128(wkv + (size_t)l * 1024 * 128, base, 1024, 128, 1024, 128,
                        1.0f, by * 128, bx * 64, 1024 + (size_t)bx * 64);
    }
  } else if (r < 272) {                 // wo: 16 x 8
    int q = r - 144, bx = q & 15, by = q >> 4;
    transpose_body128(wo + (size_t)l * 1024 * 1024, base + OFF_WO, 1024, 1024, 1024, 1024,
                      1.0f, by * 128, bx * 64, (size_t)bx * 64);
  } else if (r < 960) {                 // w1: 86 x 8
    int q = r - 272, bx = q % 86, by = q / 86;
    transpose_body128(w1 + (size_t)l * 1024 * 5460, base + OFF_W1, 1024, 5460, 1024, 5504,
                      1.0f, by * 128, bx * 64, (size_t)bx * 64);
  } else {                              // w2: 16 x 22
    int q = r - 960, bx = q & 15, by = q >> 4;
    transpose_body128(w2 + (size_t)l * 2730 * 1024, base + OFF_W2, 2730, 1024, 2752, 1024,
                      1.0f, by * 128, bx * 64, (size_t)bx * 64);
  }
}

// ---------------- LayerNorm specialized for 1024 cols ----------------
template <typename OutT>
__global__ __launch_bounds__(256) void ln1024(const float* __restrict__ in,
                                              const float* __restrict__ g,
                                              OutT* __restrict__ out) {
  int row = blockIdx.x;
  int tid = threadIdx.x;
  floatx4 v = *(const floatx4*)&in[(size_t)row * 1024 + tid * 4];
  float s = v[0] + v[1] + v[2] + v[3];
  float ss = v[0] * v[0] + v[1] * v[1] + v[2] * v[2] + v[3] * v[3];
#pragma unroll
  for (int off = 32; off; off >>= 1) {
    s  += __shfl_down(s, off, 64);
    ss += __shfl_down(ss, off, 64);
  }
  __shared__ float l1[4], l2[4];
  int wid = tid >> 6, lane = tid & 63;
  if (lane == 0) { l1[wid] = s; l2[wid] = ss; }
  __syncthreads();
  if (tid == 0) {
    float a = l1[0] + l1[1] + l1[2] + l1[3];
    float bb = l2[0] + l2[1] + l2[2] + l2[3];
    float m = a * (1.0f / 1024.0f);
    float var = bb * (1.0f / 1024.0f) - m * m;
    l1[0] = m;
    l2[0] = rsqrtf(var + 1e-5f);
  }
  __syncthreads();
  float m = l1[0], r = l2[0];
  floatx4 gv = *(const floatx4*)&g[tid * 4];
  if constexpr (sizeof(OutT) == 2) {
    short4v p;
#pragma unroll
    for (int e = 0; e < 4; e++) p[e] = (short)f2bf((v[e] - m) * r * gv[e]);
    *(short4v*)&out[(size_t)row * 1024 + tid * 4] = p;
  } else {
    floatx4 p;
#pragma unroll
    for (int e = 0; e < 4; e++) p[e] = (v[e] - m) * r * gv[e];
    *(floatx4*)&out[(size_t)row * 1024 + tid * 4] = p;
  }
}

// ---------------- bf16 MFMA GEMM, 128x128 tile, double-buffered prefetch ----------------
template <bool ADD, typename OutT>
__global__ __launch_bounds__(256) void gemm_mfma128(const ushort* __restrict__ A,
                                                    const ushort* __restrict__ Bt,
                                                    const float* __restrict__ Cin,
                                                    OutT* __restrict__ C,
                                                    int N, int K, float scale) {
  __shared__ ushort Als[2][128 * 64];
  __shared__ ushort Bls[2][128 * 64];
  int tid = threadIdx.x;
  int w = tid >> 6, lane = tid & 63;
  int wr = w >> 1, wc = w & 1;
  size_t row0 = (size_t)blockIdx.y * 128, col0 = (size_t)blockIdx.x * 128;

  const ushort* Ag = A + (row0 + w * 32 + (lane >> 3)) * (size_t)K + (lane & 7) * 8;
  const ushort* Bg = Bt + (col0 + w * 32 + (lane >> 3)) * (size_t)K + (lane & 7) * 8;
  int wbase = w * 32 * 64;   // wave's LDS region (elems); lane offset applied by HW

  floatx4 acc[4][4];
#pragma unroll
  for (int i = 0; i < 4; i++)
#pragma unroll
    for (int j = 0; j < 4; j++) { floatx4 z = {0.f, 0.f, 0.f, 0.f}; acc[i][j] = z; }

  int mrow = lane & 15, kq = (lane >> 4) * 8;
  int NT = K >> 6;

  // prologue: stage tile 0 into buffer 0 (8 ops/wave)
#pragma unroll
  for (int r = 0; r < 4; r++) {
    gload_lds16(Ag + (size_t)(r * 8) * K, &Als[0][wbase + r * 8 * 64]);
    gload_lds16(Bg + (size_t)(r * 8) * K, &Bls[0][wbase + r * 8 * 64]);
  }

  for (int t = 0; t < NT; t++) {
    const ushort* Ac = Als[t & 1];
    const ushort* Bc = Bls[t & 1];
    if (t + 1 < NT) {
      int nb = (t + 1) & 1;
      int ko = (t + 1) << 6;
#pragma unroll
      for (int r = 0; r < 4; r++) {
        gload_lds16(Ag + (size_t)(r * 8) * K + ko, &Als[nb][wbase + r * 8 * 64]);
        gload_lds16(Bg + (size_t)(r * 8) * K + ko, &Bls[nb][wbase + r * 8 * 64]);
      }
      VMCNT(8);   // wait: current tile's 8 ops landed; next tile's 8 still in flight
    } else {
      VMCNT(0);
    }
    __builtin_amdgcn_s_barrier();
#pragma unroll
    for (int kk = 0; kk < 64; kk += 32) {
      short8 a[4], b[4];
#pragma unroll
      for (int i = 0; i < 4; i++)
        a[i] = *(const short8*)&Ac[(wr * 64 + i * 16 + mrow) * 64 + kk + kq];
#pragma unroll
      for (int j = 0; j < 4; j++)
        b[j] = *(const short8*)&Bc[(wc * 64 + j * 16 + mrow) * 64 + kk + kq];
#pragma unroll
      for (int i = 0; i < 4; i++)
#pragma unroll
        for (int j = 0; j < 4; j++)
          acc[i][j] = __builtin_amdgcn_mfma_f32_16x16x32_bf16(a[i], b[j], acc[i][j], 0, 0, 0);
    }
    __builtin_amdgcn_s_barrier();
  }
  int orow = (lane >> 4) * 4, ocol = lane & 15;
#pragma unroll
  for (int i = 0; i < 4; i++) {
#pragma unroll
    for (int ii = 0; ii < 4; ii++) {
      size_t gr = row0 + wr * 64 + i * 16 + orow + ii;
#pragma unroll
      for (int j = 0; j < 4; j++) {
        size_t gc = col0 + wc * 64 + j * 16 + ocol;
        float v = acc[i][j][ii] * scale;
        if (ADD) v += Cin[gr * N + gc];
        if constexpr (sizeof(OutT) == 2) C[gr * N + gc] = f2bf(v);
        else C[gr * N + gc] = v;
      }
    }
  }
}

// ---------------- bf16 MFMA GEMM, 64x64 tile, double-buffered prefetch ----------------
// 4 waves; wave w owns all 64 rows x cols [w*16, w*16+16).
template <bool ADD, typename OutT>
__global__ __launch_bounds__(256) void gemm64x64(const ushort* __restrict__ A,
                                                 const ushort* __restrict__ Bt,
                                                 const float* __restrict__ Cin,
                                                 OutT* __restrict__ C,
                                                 int N, int K, float scale) {
  __shared__ ushort Als[2][64 * 64];
  __shared__ ushort Bls[2][64 * 64];
  int tid = threadIdx.x;
  int w = tid >> 6, lane = tid & 63;
  size_t row0 = (size_t)blockIdx.y * 64, col0 = (size_t)blockIdx.x * 64;

  const ushort* Ag = A + (row0 + (tid >> 3)) * (size_t)K + (tid & 7) * 8;
  const ushort* Bg = Bt + (col0 + (tid >> 3)) * (size_t)K + (tid & 7) * 8;
  int ldst = (tid >> 3) * 64 + (tid & 7) * 8;   // lane-linear LDS offset (elems)

  floatx4 acc[4];
#pragma unroll
  for (int i = 0; i < 4; i++) { floatx4 z = {0.f, 0.f, 0.f, 0.f}; acc[i] = z; }

  int mrow = lane & 15, kq = (lane >> 4) * 8;
  int NT = K >> 6;

  // prologue: stage tile 0 into buffer 0 (4 ops/wave)
  gload_lds16(Ag, &Als[0][ldst]);
  gload_lds16(Ag + (size_t)32 * K, &Als[0][ldst + 2048]);
  gload_lds16(Bg, &Bls[0][ldst]);
  gload_lds16(Bg + (size_t)32 * K, &Bls[0][ldst + 2048]);

  for (int t = 0; t < NT; t++) {
    const ushort* Ac = Als[t & 1];
    const ushort* Bc = Bls[t & 1];
    if (t + 1 < NT) {
      int nb = (t + 1) & 1;
      int ko = (t + 1) << 6;
      gload_lds16(Ag + ko, &Als[nb][ldst]);
      gload_lds16(Ag + (size_t)32 * K + ko, &Als[nb][ldst + 2048]);
      gload_lds16(Bg + ko, &Bls[nb][ldst]);
      gload_lds16(Bg + (size_t)32 * K + ko, &Bls[nb][ldst + 2048]);
      VMCNT(4);   // current tile landed; next tile in flight
    } else {
      VMCNT(0);
    }
    __builtin_amdgcn_s_barrier();
#pragma unroll
    for (int kk = 0; kk < 64; kk += 32) {
      short8 b = *(const short8*)&Bc[(w * 16 + mrow) * 64 + kk + kq];
#pragma unroll
      for (int i = 0; i < 4; i++) {
        short8 a = *(const short8*)&Ac[(i * 16 + mrow) * 64 + kk + kq];
        acc[i] = __builtin_amdgcn_mfma_f32_16x16x32_bf16(a, b, acc[i], 0, 0, 0);
      }
    }
    __builtin_amdgcn_s_barrier();
  }
  int orow = (lane >> 4) * 4, ocol = lane & 15;
#pragma unroll
  for (int i = 0; i < 4; i++) {
#pragma unroll
    for (int ii = 0; ii < 4; ii++) {
      size_t gr = row0 + i * 16 + orow + ii;
      size_t gc = col0 + w * 16 + ocol;
      float v = acc[i][ii] * scale;
      if (ADD) v += Cin[gr * N + gc];
      if constexpr (sizeof(OutT) == 2) C[gr * N + gc] = f2bf(v);
      else C[gr * N + gc] = v;
    }
  }
}

// ---------------- fused causal conv(3) + GLU(gelu exact) + LayerNorm -> bf16 padded ----------------
__global__ __launch_bounds__(256) void convglu_ln(const ushort* __restrict__ h1,
                                                  const float* __restrict__ cw,
                                                  const float* __restrict__ lng,
                                                  ushort* __restrict__ out) {
  int t = blockIdx.x;
  int n = t & (SEQ - 1);
  int tid = threadIdx.x;
  const ushort* r0 = h1 + (size_t)t * N1P;
  float vals[3][4];
  float s = 0.f, ss = 0.f;
#pragma unroll
  for (int it = 0; it < 3; it++) {
    int c = (it * 256 + tid) * 4;
#pragma unroll
    for (int e = 0; e < 4; e++) vals[it][e] = 0.f;
    if (c < INNER) {
      ushort4v a2 = *(const ushort4v*)&r0[c];
      ushort4v a1 = {0, 0, 0, 0}, a0 = {0, 0, 0, 0};
      if (n >= 1) a1 = *(const ushort4v*)&r0[c - N1P];
      if (n >= 2) a0 = *(const ushort4v*)&r0[c - 2 * N1P];
      int cg = c + INNER;   // ≡ 2 mod 4 -> two 4B-aligned ushort2 loads per row
      ushort2v g2a = *(const ushort2v*)&r0[cg];
      ushort2v g2b = *(const ushort2v*)&r0[cg + 2];
      ushort2v g1a = {0, 0}, g1b = {0, 0}, g0a = {0, 0}, g0b = {0, 0};
      if (n >= 1) { g1a = *(const ushort2v*)&r0[cg - N1P]; g1b = *(const ushort2v*)&r0[cg + 2 - N1P]; }
      if (n >= 2) { g0a = *(const ushort2v*)&r0[cg - 2 * N1P]; g0b = *(const ushort2v*)&r0[cg + 2 - 2 * N1P]; }
      const floatx4* cwa = (const floatx4*)(cw + (size_t)c * 3);
      floatx4 f0 = cwa[0], f1 = cwa[1], f2 = cwa[2];
      float wa[12] = {f0[0], f0[1], f0[2], f0[3], f1[0], f1[1], f1[2], f1[3],
                      f2[0], f2[1], f2[2], f2[3]};
#pragma unroll
      for (int e = 0; e < 4; e++) {
        int ce = c + e;
        if (ce < INNER) {
          float av = bf2f(a0[e]) * wa[e * 3] + bf2f(a1[e]) * wa[e * 3 + 1] +
                     bf2f(a2[e]) * wa[e * 3 + 2];
          int cge = ce + INNER;
          float w0g = cw[cge * 3], w1g = cw[cge * 3 + 1], w2g = cw[cge * 3 + 2];
          float g0f = bf2f(e < 2 ? g0a[e & 1] : g0b[e & 1]);
          float g1f = bf2f(e < 2 ? g1a[e & 1] : g1b[e & 1]);
          float g2f = bf2f(e < 2 ? g2a[e & 1] : g2b[e & 1]);
          float gvv = g0f * w0g + g1f * w1g + g2f * w2g;
          float gl = 0.5f * gvv * (1.0f + erff(gvv * 0.70710678118654752f));
          float val = gl * av;
          vals[it][e] = val;
          s += val;
          ss += val * val;
        }
      }
    }
  }
#pragma unroll
  for (int off = 32; off; off >>= 1) {
    s  += __shfl_down(s, off, 64);
    ss += __shfl_down(ss, off, 64);
  }
  __shared__ float l1[4], l2[4];
  int wid = tid >> 6, lane = tid & 63;
  if (lane == 0) { l1[wid] = s; l2[wid] = ss; }
  __syncthreads();
  if (tid == 0) {
    float a = l1[0] + l1[1] + l1[2] + l1[3];
    float bb = l2[0] + l2[1] + l2[2] + l2[3];
    float m = a * (1.0f / INNER);
    float var = bb * (1.0f / INNER) - m * m;
    l1[0] = m;
    l2[0] = rsqrtf(var + 1e-5f);
  }
  __syncthreads();
  float m = l1[0], r = l2[0];
#pragma unroll
  for (int it = 0; it < 3; it++) {
    int c = (it * 256 + tid) * 4;
    if (c < INNERP) {
      short4v p;
#pragma unroll
      for (int e = 0; e < 4; e++) {
        int ce = c + e;
        p[e] = (ce < INNER) ? (short)f2bf((vals[it][e] - m) * r * lng[ce]) : (short)0;
      }
      *(short4v*)&out[(size_t)t * INNERP + c] = p;
    }
  }
}

// ---------------- MFMA flash attention ----------------
__global__ __launch_bounds__(256) void attn_mfma(const ushort* __restrict__ qkv,
                                                 const float* __restrict__ bias_c,
                                                 ushort* __restrict__ o) {
  __shared__ ushort Ks[64 * 72];
  __shared__ ushort Vt[64 * 72];
  __shared__ ushort Ps[64 * 72];
  __shared__ float arow[64];
  int tid = threadIdx.x;
  int lane = tid & 63, w = tid >> 6;
  int quad = lane >> 4, col = lane & 15;
  int b = blockIdx.x >> 4, h = blockIdx.x & 15;
  int y = blockIdx.y;
  int qt = (y < 8) ? (15 - y) : (y - 8);

  const ushort* qrow = qkv + (size_t)(b * SEQ + qt * 64 + w * 16 + col) * QKVW + h * 64;
  short8 qa[2];
  qa[0] = *(const short8*)&qrow[quad * 8];
  qa[1] = *(const short8*)&qrow[32 + quad * 8];

  float m_[4], l_[4];
  floatx4 oacc[4];
#pragma unroll
  for (int r = 0; r < 4; r++) { m_[r] = -1e30f; l_[r] = 0.f; }
#pragma unroll
  for (int mt = 0; mt < 4; mt++) { floatx4 z = {0.f, 0.f, 0.f, 0.f}; oacc[mt] = z; }

  for (int kc = 0; kc <= qt; kc++) {
    const ushort* kvb = qkv + (size_t)(b * SEQ + kc * 64) * QKVW;
#pragma unroll
    for (int it = 0; it < 2; it++) {
      int r = lane;
      int c8 = w + it * 4;
      short8 kk8 = *(const short8*)&kvb[(size_t)r * QKVW + 1024 + c8 * 8];
      *(short8*)&Ks[r * 72 + c8 * 8] = kk8;
      short8 vv = *(const short8*)&kvb[(size_t)r * QKVW + 1088 + c8 * 8];
#pragma unroll
      for (int e = 0; e < 8; e++) Vt[(c8 * 8 + e) * 72 + r] = (ushort)vv[e];
    }
    __syncthreads();

    floatx4 sarr[4];
#pragma unroll
    for (int j = 0; j < 4; j++) { floatx4 z = {0.f, 0.f, 0.f, 0.f}; sarr[j] = z; }
#pragma unroll
    for (int kk = 0; kk < 2; kk++) {
#pragma unroll
      for (int j = 0; j < 4; j++) {
        short8 kb = *(const short8*)&Ks[(j * 16 + col) * 72 + kk * 32 + quad * 8];
        sarr[j] = __builtin_amdgcn_mfma_f32_16x16x32_bf16(qa[kk], kb, sarr[j], 0, 0, 0);
      }
    }

    int dq = qt - kc;
    const floatx4* bc = (const floatx4*)(bias_c + ((size_t)(h * 16 + dq) * 4096 + (w * 4 + quad) * 256));
    float pv[4][4];
#pragma unroll
    for (int j = 0; j < 4; j++) {
      floatx4 bf = bc[j * 16 + col];
#pragma unroll
      for (int reg = 0; reg < 4; reg++) {
        float v = sarr[j][reg] + bf[reg];
        if (dq == 0 && (j * 16 + col) > (w * 16 + quad * 4 + reg)) v = -1e30f;
        pv[j][reg] = v;
      }
    }

#pragma unroll
    for (int reg = 0; reg < 4; reg++) {
      float cm = fmaxf(fmaxf(pv[0][reg], pv[1][reg]), fmaxf(pv[2][reg], pv[3][reg]));
      cm = fmaxf(cm, __shfl_xor(cm, 1, 64));
      cm = fmaxf(cm, __shfl_xor(cm, 2, 64));
      cm = fmaxf(cm, __shfl_xor(cm, 4, 64));
      cm = fmaxf(cm, __shfl_xor(cm, 8, 64));
      float nm = fmaxf(m_[reg], cm);
      float alpha = __expf(m_[reg] - nm);
      float rs = 0.f;
#pragma unroll
      for (int j = 0; j < 4; j++) {
        float e = __expf(pv[j][reg] - nm);
        pv[j][reg] = e;
        rs += e;
      }
      rs += __shfl_xor(rs, 1, 64);
      rs += __shfl_xor(rs, 2, 64);
      rs += __shfl_xor(rs, 4, 64);
      rs += __shfl_xor(rs, 8, 64);
      l_[reg] = l_[reg] * alpha + rs;
      m_[reg] = nm;
      if (col == 0) arow[w * 16 + quad * 4 + reg] = alpha;
    }

#pragma unroll
    for (int j = 0; j < 4; j++)
#pragma unroll
      for (int reg = 0; reg < 4; reg++)
        Ps[(w * 16 + quad * 4 + reg) * 72 + j * 16 + col] = f2bf(pv[j][reg]);

    asm volatile("s_waitcnt lgkmcnt(0)" ::: "memory");
    float aval = arow[w * 16 + col];
#pragma unroll
    for (int mt = 0; mt < 4; mt++) oacc[mt] *= aval;

#pragma unroll
    for (int kk = 0; kk < 2; kk++) {
      short8 pb = *(const short8*)&Ps[(w * 16 + col) * 72 + kk * 32 + quad * 8];
#pragma unroll
      for (int mt = 0; mt < 4; mt++) {
        short8 va = *(const short8*)&Vt[(mt * 16 + col) * 72 + kk * 32 + quad * 8];
        oacc[mt] = __builtin_amdgcn_mfma_f32_16x16x32_bf16(va, pb, oacc[mt], 0, 0, 0);
      }
    }
    __syncthreads();
  }

#pragma unroll
  for (int reg = 0; reg < 4; reg++)
    if (col == 0) arow[w * 16 + quad * 4 + reg] = 1.0f / l_[reg];
  asm volatile("s_waitcnt lgkmcnt(0)" ::: "memory");
  float lv = arow[w * 16 + col];
  size_t obase = (size_t)(b * SEQ + qt * 64 + w * 16 + col) * 1024 + h * 64;
#pragma unroll
  for (int mt = 0; mt < 4; mt++) {
    short4v pk;
#pragma unroll
    for (int reg = 0; reg < 4; reg++) pk[reg] = (short)f2bf(oacc[mt][reg] * lv);
    *(short4v*)&o[obase + mt * 16 + quad * 4] = pk;
  }
}

// ---------------- launch ----------------
extern "C" void kernel_launch(void* const* d_in, const int* in_sizes, int n_in,
                              void* d_out, int out_size, void* d_ws, size_t ws_size,
                              hipStream_t stream) {
  const float* x_in    = (const float*)d_in[0];
  const float* rel_emb = (const float*)d_in[1];
  const float* qn_g    = (const float*)d_in[2];
  const float* wq      = (const float*)d_in[3];
  const float* wkv     = (const float*)d_in[4];
  const float* wo      = (const float*)d_in[5];
  const float* ln1_g   = (const float*)d_in[6];
  const float* w1      = (const float*)d_in[7];
  const float* convw   = (const float*)d_in[8];
  const float* ln2_g   = (const float*)d_in[9];
  const float* w2      = (const float*)d_in[10];
  const float* final_g = (const float*)d_in[11];
  float* out = (float*)d_out;

  // ws layout, no aliasing
  float* xbuf   = (float*)d_ws;                              // TOK*DIM f32
  float* bias_c = xbuf + (size_t)TOK * DIM;                  // 16*16*4096 f32
  ushort* hbuf  = (ushort*)(bias_c + (size_t)16 * 16 * 4096);
  ushort* obuf  = hbuf + (size_t)TOK * DIM;
  ushort* qkvbuf = obuf + (size_t)TOK * DIM;
  ushort* h1buf = qkvbuf + (size_t)TOK * QKVW;
  ushort* gbuf  = h1buf + (size_t)TOK * N1P;
  ushort* wtall = gbuf + (size_t)TOK * INNERP;

  size_t need = (size_t)((char*)(wtall + 6ull * LWT) - (char*)d_ws);
  bool big = ws_size >= need;   // ~188 MB: all-layer transposed weights resident

  bias_frag_kernel<<<256, 256, 0, stream>>>(rel_emb, bias_c);
  if (big)
    transpose_all<<<6 * TILES_PER_LAYER, 256, 0, stream>>>(wq, wkv, wo, w1, w2, wtall);

  for (int l = 0; l < DEPTH; l++) {
    // x*ALPHA + stop_grad(x)*(1-ALPHA) == x, so layer 0 reads x_in directly.
    const float* xres = (l == 0) ? x_in : xbuf;
    const ushort *wtq, *wto, *wt1, *wt2;
    if (big) {
      const ushort* bl = wtall + (size_t)l * LWT;
      wtq = bl; wto = bl + OFF_WO; wt1 = bl + OFF_W1; wt2 = bl + OFF_W2;
    } else {
      wtq = wto = wt1 = wt2 = wtall;
    }

    ln1024<ushort><<<TOK, 256, 0, stream>>>(xres, qn_g + l * DIM, hbuf);
    if (!big)
      transpose_qkv<<<dim3(18, 16), 256, 0, stream>>>(
          wq + (size_t)l * DIM * DIM, wkv + (size_t)l * DIM * 128, (ushort*)wtall);
    gemm64x64<false, ushort><<<dim3(18, 32), 256, 0, stream>>>(
        hbuf, wtq, nullptr, qkvbuf, QKVW, DIM, 1.0f);
    attn_mfma<<<dim3(BATCH * HEADS, 16), 256, 0, stream>>>(qkvbuf, bias_c, obuf);
    if (!big)
      transpose_vec<<<dim3(16, 16), 256, 0, stream>>>(
          wo + (size_t)l * DIM * DIM, (ushort*)wtall, DIM, DIM, DIM, DIM, 1.0f);
    gemm64x64<true, float><<<dim3(16, 32), 256, 0, stream>>>(
        obuf, wto, xres, xbuf, DIM, DIM, 1.0f);
    ln1024<ushort><<<TOK, 256, 0, stream>>>(xbuf, ln1_g + l * DIM, hbuf);
    if (!big)
      transpose_vec<<<dim3(86, 16), 256, 0, stream>>>(
          w1 + (size_t)l * DIM * INNER2, (ushort*)wtall, DIM, INNER2, DIM, N1P, 1.0f);
    gemm_mfma128<false, ushort><<<dim3(43, 16), 256, 0, stream>>>(
        hbuf, wt1, nullptr, h1buf, N1P, DIM, 1.0f);
    convglu_ln<<<TOK, 256, 0, stream>>>(
        h1buf, convw + (size_t)l * INNER2 * 3, ln2_g + l * INNER, gbuf);
    if (!big)
      transpose_vec<<<dim3(16, 43), 256, 0, stream>>>(
          w2 + (size_t)l * INNER * DIM, (ushort*)wtall, INNER, DIM, INNERP, DIM, 1.0f);
    gemm64x64<true, float><<<dim3(16, 32), 256, 0, stream>>>(
        gbuf, wt2, xbuf, xbuf, DIM, INNERP, 1.0f);
  }
  ln1024<float><<<TOK, 256, 0, stream>>>(xbuf, final_g, out);
}